// Round 6
// baseline (48654.208 us; speedup 1.0000x reference)
//
#include <hip/hip_runtime.h>

#define N_PTS 40000
#define C_IN 64
#define C_OUT 128
#define K_NN 16
#define M_SAMPLES 10001   // int(40000*0.25)+1

#define GRID_DIM 16
#define NCELLS 4096       // 16^3

// Exact reference arithmetic: (dx*dx + dy*dy) + dz*dz, no FMA contraction.
__device__ __forceinline__ float dist3_exact(float dx, float dy, float dz) {
#pragma clang fp contract(off)
  return (dx * dx + dy * dy) + dz * dz;
}

__device__ __forceinline__ int cell_of(float x, float y, float z) {
  int cx = min(GRID_DIM - 1, max(0, (int)(x * 1.6f)));
  int cy = min(GRID_DIM - 1, max(0, (int)(y * 1.6f)));
  int cz = min(GRID_DIM - 1, max(0, (int)(z * 1.6f)));
  return (cx << 8) | (cy << 4) | cz;
}

// ---------------- bucketing prologue ----------------
__global__ void hist_kernel(const float* __restrict__ xyz, int* __restrict__ hist) {
  int p = blockIdx.x * 256 + threadIdx.x;
  if (p < N_PTS) {
    int c = cell_of(xyz[3 * p], xyz[3 * p + 1], xyz[3 * p + 2]);
    atomicAdd(&hist[c], 1);
  }
}

// 4096-entry exclusive scan -> start[4097] and cursor[4096]
__global__ __launch_bounds__(1024) void scan_kernel(const int* __restrict__ hist,
                                                    int* __restrict__ start,
                                                    int* __restrict__ cursor) {
  __shared__ int tmp[1024];
  int t = threadIdx.x;
  int4 h = ((const int4*)hist)[t];
  int s4 = h.x + h.y + h.z + h.w;
  tmp[t] = s4;
  __syncthreads();
  for (int off = 1; off < 1024; off <<= 1) {
    int v = tmp[t];
    int u = (t >= off) ? tmp[t - off] : 0;
    __syncthreads();
    tmp[t] = v + u;
    __syncthreads();
  }
  int excl = (t == 0) ? 0 : tmp[t - 1];
  int4 o;
  o.x = excl; o.y = excl + h.x; o.z = excl + h.x + h.y; o.w = excl + h.x + h.y + h.z;
  ((int4*)start)[t] = o;
  ((int4*)cursor)[t] = o;
  if (t == 1023) start[NCELLS] = excl + s4;  // == 40000
}

// pts4[slot] = {x, y, z, bitcast(original_index)}; exact per-cell bbox via
// atomic min/max on u32 bits (coords >= 0 -> bit pattern is order-monotone).
__global__ void scatter_kernel(const float* __restrict__ xyz, int* __restrict__ cursor,
                               float4* __restrict__ pts4,
                               unsigned* __restrict__ bmin,
                               unsigned* __restrict__ bmax) {
  int p = blockIdx.x * 256 + threadIdx.x;
  if (p < N_PTS) {
    float x = xyz[3 * p], y = xyz[3 * p + 1], z = xyz[3 * p + 2];
    int c = cell_of(x, y, z);
    int pos = atomicAdd(&cursor[c], 1);
    float4 v;
    v.x = x; v.y = y; v.z = z; v.w = __uint_as_float((unsigned)p);
    pts4[pos] = v;
    atomicMin(&bmin[c * 3 + 0], __float_as_uint(x));
    atomicMin(&bmin[c * 3 + 1], __float_as_uint(y));
    atomicMin(&bmin[c * 3 + 2], __float_as_uint(z));
    atomicMax(&bmax[c * 3 + 0], __float_as_uint(x));
    atomicMax(&bmax[c * 3 + 1], __float_as_uint(y));
    atomicMax(&bmax[c * 3 + 2], __float_as_uint(z));
  }
}

// ---- pruned FPS: per-lane micro-cells, chunked prefetch, 1 barrier/iter ----
__global__ __launch_bounds__(1024) void fps_kernel(
    const float* __restrict__ xyz, const float4* __restrict__ pts4,
    const int* __restrict__ start, const unsigned* __restrict__ bmin,
    const unsigned* __restrict__ bmax, float* __restrict__ nxyz_out) {
  __shared__ float dist_s[N_PTS];                 // 160000 B
  __shared__ unsigned long long wkey_s[2][16];
  __shared__ float4 wxyz_s[2][16];

  const int t = threadIdx.x;
  const int lane = t & 63;
  const int w = t >> 6;  // wave 0..15

  for (int i = t; i < N_PTS; i += 1024) dist_s[i] = 1e10f;

  // my 4 cells via Morton bits: m = (k<<10)|(lane<<4)|w, deinterleaved ->
  // spatially-adjacent cells land on different (wave,lane) => load balance.
  int cs[4], cn[4];
  float blo[4][3], bhi[4][3];
  float cmax[4];
  unsigned cidx[4];
  float cbx[4], cby[4], cbz[4];
#pragma unroll
  for (int k = 0; k < 4; ++k) {
    int m = (k << 10) | (lane << 4) | w;
    int cx = 0, cy = 0, cz = 0;
#pragma unroll
    for (int b = 0; b < 4; ++b) {
      cx |= ((m >> (3 * b)) & 1) << b;
      cy |= ((m >> (3 * b + 1)) & 1) << b;
      cz |= ((m >> (3 * b + 2)) & 1) << b;
    }
    int c = (cx << 8) | (cy << 4) | cz;
    cs[k] = start[c];
    cn[k] = start[c + 1] - cs[k];
#pragma unroll
    for (int d = 0; d < 3; ++d) {
      blo[k][d] = __uint_as_float(bmin[c * 3 + d]);
      bhi[k][d] = __uint_as_float(bmax[c * 3 + d]);
    }
    cmax[k] = (cn[k] > 0) ? 1e10f : -1.0f;  // nonempty cells all-active at s=0
    cidx[k] = 0xffffffffu;
    cbx[k] = 0.f; cby[k] = 0.f; cbz[k] = 0.f;
  }
  float lx = xyz[0], ly = xyz[1], lz = xyz[2];  // center 0 = point 0
  __syncthreads();

  for (int s = 0; s < M_SAMPLES; ++s) {
    const int par = s & 1;
    if (t == 0) {
      nxyz_out[3 * s + 0] = lx;
      nxyz_out[3 * s + 1] = ly;
      nxyz_out[3 * s + 2] = lz;
    }
#pragma unroll
    for (int k = 0; k < 4; ++k) {
      // conservative skip test against exact point bbox (0.9999 rel margin)
      float ex = fmaxf(fmaxf(blo[k][0] - lx, lx - bhi[k][0]), 0.f);
      float ey = fmaxf(fmaxf(blo[k][1] - ly, ly - bhi[k][1]), 0.f);
      float ez = fmaxf(fmaxf(blo[k][2] - lz, lz - bhi[k][2]), 0.f);
      float lb = ex * ex + ey * ey + ez * ez;
      if (lb * 0.9999f >= cmax[k]) continue;  // empty cells: cmax=-1 -> skip
      // recompute this cell: 8-deep batched loads (one wait per chunk)
      float md = -1.f;
      unsigned mi = 0xffffffffu;
      float mx2 = 0.f, my2 = 0.f, mz2 = 0.f;
      const int base = cs[k], n = cn[k];
      for (int j = 0; j < n; j += 8) {
        float4 B[8];
        const int c8 = min(8, n - j);
#pragma unroll
        for (int u = 0; u < 8; ++u)
          if (u < c8) B[u] = pts4[base + j + u];
#pragma unroll
        for (int u = 0; u < 8; ++u)
          if (u < c8) {
            float dx, dy, dz;
            {
#pragma clang fp contract(off)
              dx = B[u].x - lx; dy = B[u].y - ly; dz = B[u].z - lz;
            }
            float d = dist3_exact(dx, dy, dz);
            const int slot = base + j + u;
            float nd = fminf(dist_s[slot], d);
            dist_s[slot] = nd;
            unsigned pi = __float_as_uint(B[u].w);
            bool better = (nd > md) || (nd == md && pi < mi);
            if (better) { md = nd; mi = pi; mx2 = B[u].x; my2 = B[u].y; mz2 = B[u].z; }
          }
      }
      cmax[k] = md; cidx[k] = mi; cbx[k] = mx2; cby[k] = my2; cbz[k] = mz2;
    }
    // lane fold over its 4 cells (lexicographic: max dist, then min idx)
    float Ld = -1.f;
    unsigned Li = 0xffffffffu;
    float Lx = 0.f, Ly = 0.f, Lz = 0.f;
#pragma unroll
    for (int k = 0; k < 4; ++k) {
      bool better = (cmax[k] > Ld) || (cmax[k] == Ld && cidx[k] < Li);
      if (cn[k] > 0 && better) {
        Ld = cmax[k]; Li = cidx[k]; Lx = cbx[k]; Ly = cby[k]; Lz = cbz[k];
      }
    }
    unsigned long long key =
        (Ld >= 0.f)
            ? (((unsigned long long)__float_as_uint(Ld) << 32) |
               (unsigned long long)(~Li))
            : 0ull;
    unsigned long long rk = key;
#pragma unroll
    for (int off = 32; off > 0; off >>= 1) {
      unsigned long long ok = __shfl_xor(rk, off);
      if (ok > rk) rk = ok;
    }
    // same key => same (dist,idx) => same point: any attaining lane's coords OK
    unsigned long long bm = __ballot(key == rk && rk != 0ull);
    int wl = __ffsll((long long)bm) - 1;
    if (wl < 0) wl = 0;
    float bx = __shfl(Lx, wl), by = __shfl(Ly, wl), bz = __shfl(Lz, wl);
    if (lane == 0) {
      wkey_s[par][w] = rk;
      float4 v; v.x = bx; v.y = by; v.z = bz; v.w = 0.f;
      wxyz_s[par][w] = v;
    }
    __syncthreads();  // the ONLY barrier per iteration
    unsigned long long best = wkey_s[par][0];
    int wi = 0;
#pragma unroll
    for (int i = 1; i < 16; ++i) {
      unsigned long long v = wkey_s[par][i];
      if (v > best) { best = v; wi = i; }
    }
    float4 cc = wxyz_s[par][wi];
    lx = cc.x; ly = cc.y; lz = cc.z;
  }
}

// ---------------- KNN: one wave per center ----------------
#define KNN_TILE 2048

__device__ __forceinline__ float knn_dist_exact(float sn, float cx, float cy,
                                                float cz, float x, float y,
                                                float z) {
#pragma clang fp contract(off)
  float sx = (x * x + y * y) + z * z;
  float dot = (cx * x + cy * y) + cz * z;
  return (sn - 2.0f * dot) + sx;
}

__global__ __launch_bounds__(256) void knn_kernel(
    const float* __restrict__ xyz, const float* __restrict__ nxyz,
    int* __restrict__ knn_out) {
  __shared__ float txyz[KNN_TILE * 3];
  const int lane = threadIdx.x & 63;
  const int wv = threadIdx.x >> 6;
  const int m = blockIdx.x * 4 + wv;
  const bool active = (m < M_SAMPLES);

  float cx = 0.f, cy = 0.f, cz = 0.f;
  if (active) {
    cx = nxyz[3 * m + 0]; cy = nxyz[3 * m + 1]; cz = nxyz[3 * m + 2];
  }
  float sn;
  {
#pragma clang fp contract(off)
    sn = (cx * cx + cy * cy) + cz * cz;
  }

  float hd[K_NN];
  int hi[K_NN];
#pragma unroll
  for (int i = 0; i < K_NN; ++i) { hd[i] = 3.4e38f; hi[i] = 0x7fffffff; }

  for (int base = 0; base < N_PTS; base += KNN_TILE) {
    const int cnt = min(KNN_TILE, N_PTS - base);
    __syncthreads();
    {
      const float4* src4 = (const float4*)(xyz + (size_t)base * 3);
      float4* dst4 = (float4*)txyz;
      const int n4 = (cnt * 3) >> 2;
      for (int i = threadIdx.x; i < n4; i += 256) dst4[i] = src4[i];
    }
    __syncthreads();
    for (int p = lane; p < cnt; p += 64) {
      float x = txyz[3 * p + 0], y = txyz[3 * p + 1], z = txyz[3 * p + 2];
      float d = knn_dist_exact(sn, cx, cy, cz, x, y, z);
      int gi = base + p;
      if (d < hd[K_NN - 1] || (d == hd[K_NN - 1] && gi < hi[K_NN - 1])) {
        hd[K_NN - 1] = d;
        hi[K_NN - 1] = gi;
#pragma unroll
        for (int i = K_NN - 1; i > 0; --i) {
          bool sw = (hd[i] < hd[i - 1]) ||
                    (hd[i] == hd[i - 1] && hi[i] < hi[i - 1]);
          if (sw) {
            float td = hd[i]; hd[i] = hd[i - 1]; hd[i - 1] = td;
            int ti = hi[i]; hi[i] = hi[i - 1]; hi[i - 1] = ti;
          }
        }
      }
    }
  }

  int keep = 0;
#pragma unroll 1
  for (int r = 0; r < K_NN; ++r) {
    float d0 = hd[0];
    int i0 = hi[0];
    int l0 = lane;
#pragma unroll
    for (int off = 32; off > 0; off >>= 1) {
      float od = __shfl_xor(d0, off);
      int oi = __shfl_xor(i0, off);
      int ol = __shfl_xor(l0, off);
      if (od < d0 || (od == d0 && oi < i0)) { d0 = od; i0 = oi; l0 = ol; }
    }
    if (lane == r) keep = i0;
    if (lane == l0) {
#pragma unroll
      for (int i = 0; i < K_NN - 1; ++i) { hd[i] = hd[i + 1]; hi[i] = hi[i + 1]; }
      hd[K_NN - 1] = 3.4e38f;
      hi[K_NN - 1] = 0x7fffffff;
    }
  }
  if (active && lane < K_NN) knn_out[m * K_NN + lane] = keep;
}

// -------- gather + LayerNorm + Linear + maxpool: one block per center --------
__global__ __launch_bounds__(128) void head_kernel(
    const float* __restrict__ feats, const int* __restrict__ knn,
    const float* __restrict__ lnw, const float* __restrict__ lnb,
    const float* __restrict__ W, float* __restrict__ out,
    float* __restrict__ noff) {
  const int m = blockIdx.x;
  const int t = threadIdx.x;
  __shared__ float g[K_NN][68];
  __shared__ float mu_s[K_NN], rs_s[K_NN];

  for (int q = t; q < 256; q += 128) {
    int k = q >> 4, c4 = q & 15;
    int src = knn[m * K_NN + k];
    float4 v = ((const float4*)(feats + (size_t)src * C_IN))[c4];
    g[k][c4 * 4 + 0] = v.x;
    g[k][c4 * 4 + 1] = v.y;
    g[k][c4 * 4 + 2] = v.z;
    g[k][c4 * 4 + 3] = v.w;
  }
  __syncthreads();
  if (t < K_NN) {
    float s = 0.f;
    for (int c = 0; c < C_IN; ++c) s += g[t][c];
    float mu = s * (1.0f / 64.0f);
    float v = 0.f;
    for (int c = 0; c < C_IN; ++c) {
      float d = g[t][c] - mu;
      v += d * d;
    }
    v *= (1.0f / 64.0f);
    mu_s[t] = mu;
    rs_s[t] = rsqrtf(v + 1e-5f);
  }
  __syncthreads();
  for (int q = t; q < K_NN * C_IN; q += 128) {
    int k = q >> 6, c = q & 63;
    g[k][c] = (g[k][c] - mu_s[k]) * rs_s[k] * lnw[c] + lnb[c];
  }
  __syncthreads();
  float acc[K_NN];
#pragma unroll
  for (int k = 0; k < K_NN; ++k) acc[k] = 0.f;
  for (int c = 0; c < C_IN; ++c) {
    float wv = W[c * C_OUT + t];
#pragma unroll
    for (int k = 0; k < K_NN; ++k) acc[k] = fmaf(g[k][c], wv, acc[k]);
  }
  float mx = acc[0];
#pragma unroll
  for (int k = 1; k < K_NN; ++k) mx = fmaxf(mx, acc[k]);
  out[(size_t)m * C_OUT + t] = mx;

  if (m == 0 && t == 0) noff[0] = (float)M_SAMPLES;
}

extern "C" void kernel_launch(void* const* d_in, const int* in_sizes, int n_in,
                              void* d_out, int out_size, void* d_ws,
                              size_t ws_size, hipStream_t stream) {
  const float* feats = (const float*)d_in[0];
  const float* xyz = (const float*)d_in[1];
  const float* lnw = (const float*)d_in[3];
  const float* lnb = (const float*)d_in[4];
  const float* W = (const float*)d_in[5];

  float* out = (float*)d_out;
  float* nxyz = out + (size_t)M_SAMPLES * C_OUT;
  float* noff = nxyz + (size_t)M_SAMPLES * 3;

  char* ws = (char*)d_ws;
  int* hist = (int*)(ws + 0);              // 4096 ints  = 16384 B
  int* cursor = (int*)(ws + 16384);        // 4096 ints  = 16384 B
  int* start = (int*)(ws + 32768);         // 4097 ints  -> pad to 16512 B
  unsigned* bmin = (unsigned*)(ws + 49280);  // 4096*3 u32 = 49152 B
  unsigned* bmax = (unsigned*)(ws + 98432);  // 4096*3 u32 = 49152 B
  float4* pts4 = (float4*)(ws + 147584);     // 40000*16   = 640000 B
  int* knn = (int*)(ws + 787584);            // 10001*16 ints

  hipMemsetAsync(hist, 0, NCELLS * sizeof(int), stream);
  hipMemsetAsync(bmin, 0x7F, NCELLS * 3 * sizeof(unsigned), stream);  // big f32
  hipMemsetAsync(bmax, 0x00, NCELLS * 3 * sizeof(unsigned), stream);  // +0.0
  hist_kernel<<<(N_PTS + 255) / 256, 256, 0, stream>>>(xyz, hist);
  scan_kernel<<<1, 1024, 0, stream>>>(hist, start, cursor);
  scatter_kernel<<<(N_PTS + 255) / 256, 256, 0, stream>>>(xyz, cursor, pts4,
                                                          bmin, bmax);
  fps_kernel<<<1, 1024, 0, stream>>>(xyz, pts4, start, bmin, bmax, nxyz);
  knn_kernel<<<(M_SAMPLES + 3) / 4, 256, 0, stream>>>(xyz, nxyz, knn);
  head_kernel<<<M_SAMPLES, 128, 0, stream>>>(feats, knn, lnw, lnb, W, out, noff);
}

// Round 7
// 30536.389 us; speedup vs baseline: 1.5933x; 1.5933x over previous
//
#include <hip/hip_runtime.h>

#define N_PTS 40000
#define C_IN 64
#define C_OUT 128
#define K_NN 16
#define M_SAMPLES 10001   // int(40000*0.25)+1

#define NGROUPS 625       // 40000 / 64, exact
#define GRID_DIM 8        // 8x8x8 buckets over [0,10)^3

// Exact reference arithmetic: (dx*dx + dy*dy) + dz*dz, no FMA contraction.
__device__ __forceinline__ float dist3_exact(float dx, float dy, float dz) {
#pragma clang fp contract(off)
  return (dx * dx + dy * dy) + dz * dz;
}

__device__ __forceinline__ int cell_of(float x, float y, float z) {
  int cx = min(GRID_DIM - 1, max(0, (int)(x * 0.8f)));
  int cy = min(GRID_DIM - 1, max(0, (int)(y * 0.8f)));
  int cz = min(GRID_DIM - 1, max(0, (int)(z * 0.8f)));
  return (cx << 6) | (cy << 3) | cz;
}

// ---------------- bucketing prologue ----------------
__global__ void hist_kernel(const float* __restrict__ xyz, int* __restrict__ hist) {
  int p = blockIdx.x * 256 + threadIdx.x;
  if (p < N_PTS) {
    int c = cell_of(xyz[3 * p], xyz[3 * p + 1], xyz[3 * p + 2]);
    atomicAdd(&hist[c], 1);
  }
}

__global__ __launch_bounds__(512) void scan_kernel(const int* __restrict__ hist,
                                                   int* __restrict__ cursor) {
  __shared__ int tmp[512];
  int t = threadIdx.x;
  tmp[t] = hist[t];
  __syncthreads();
  for (int off = 1; off < 512; off <<= 1) {
    int v = tmp[t];
    int u = (t >= off) ? tmp[t - off] : 0;
    __syncthreads();
    tmp[t] = v + u;
    __syncthreads();
  }
  cursor[t] = (t == 0) ? 0 : tmp[t - 1];
}

// pts4[slot] = {x, y, z, bitcast(original_index)}
__global__ void scatter_kernel(const float* __restrict__ xyz, int* __restrict__ cursor,
                               float4* __restrict__ pts4) {
  int p = blockIdx.x * 256 + threadIdx.x;
  if (p < N_PTS) {
    float x = xyz[3 * p], y = xyz[3 * p + 1], z = xyz[3 * p + 2];
    int c = cell_of(x, y, z);
    int pos = atomicAdd(&cursor[c], 1);
    float4 v;
    v.x = x; v.y = y; v.z = z; v.w = __uint_as_float((unsigned)p);
    pts4[pos] = v;
  }
}

// bboxg[g*8 + {0..5}] = exact bbox of sorted 64-pt chunk g
__global__ __launch_bounds__(64) void bbox_kernel(const float4* __restrict__ pts4,
                                                  float* __restrict__ bboxg) {
  int g = blockIdx.x, lane = threadIdx.x;
  float4 P = pts4[g * 64 + lane];
  float lox = P.x, hix = P.x, loy = P.y, hiy = P.y, loz = P.z, hiz = P.z;
#pragma unroll
  for (int off = 32; off > 0; off >>= 1) {
    lox = fminf(lox, __shfl_xor(lox, off)); hix = fmaxf(hix, __shfl_xor(hix, off));
    loy = fminf(loy, __shfl_xor(loy, off)); hiy = fmaxf(hiy, __shfl_xor(hiy, off));
    loz = fminf(loz, __shfl_xor(loz, off)); hiz = fmaxf(hiz, __shfl_xor(hiz, off));
  }
  if (lane == 0) {
    bboxg[g * 8 + 0] = lox; bboxg[g * 8 + 1] = hix;
    bboxg[g * 8 + 2] = loy; bboxg[g * 8 + 3] = hiy;
    bboxg[g * 8 + 4] = loz; bboxg[g * 8 + 5] = hiz;
    bboxg[g * 8 + 6] = 0.f; bboxg[g * 8 + 7] = 0.f;
  }
}

// ---- pruned FPS: 4-way interleaved groups, f32 reduces, LDS coords ----
__global__ __launch_bounds__(1024) void fps_kernel(
    const float* __restrict__ xyz, const float4* __restrict__ pts4,
    const float* __restrict__ bboxg, float* __restrict__ nxyz_out) {
  __shared__ float dist_s[N_PTS];                 // 160000 B
  __shared__ unsigned long long wkey_s[2][16];
  __shared__ float4 wxyz_s[2][16];

  const int t = threadIdx.x;
  const int lane = t & 63;
  const int w = t >> 6;                  // wave 0..15
  const int nloc = (624 - w) / 16 + 1;   // lane l (< nloc) owns group w+16*l
  const bool owner = (lane < nloc);

  for (int i = t; i < N_PTS; i += 1024) dist_s[i] = 1e10f;

  // owner-lane persistent state
  float blox = 0.f, bhix = 0.f, bloy = 0.f, bhiy = 0.f, bloz = 0.f, bhiz = 0.f;
  float gmax = -1.f;                 // group's current max of min-dists
  unsigned gidx = 0xffffffffu;       // its argmax (min original idx on ties)
  float gx_ = 0.f, gy_ = 0.f, gz_ = 0.f;  // that point's coords (bitwise xyz)
  if (owner) {
    int g = w + 16 * lane;
    const float4* b4 = (const float4*)(bboxg + g * 8);
    float4 v0 = b4[0], v1 = b4[1];
    blox = v0.x; bhix = v0.y; bloy = v0.z; bhiy = v0.w;
    bloz = v1.x; bhiz = v1.y;
    gmax = 1e10f;  // forces all-active at s=0
  }
  float lx = xyz[0], ly = xyz[1], lz = xyz[2];  // center 0 = point 0
  __syncthreads();

  for (int s = 0; s < M_SAMPLES; ++s) {
    const int par = s & 1;
    if (t == 0) {
      nxyz_out[3 * s + 0] = lx;
      nxyz_out[3 * s + 1] = ly;
      nxyz_out[3 * s + 2] = lz;
    }
    // ---- A: conservative skip test (registers only) ----
    bool active = false;
    if (owner) {
      float ex = fmaxf(fmaxf(blox - lx, lx - bhix), 0.f);
      float ey = fmaxf(fmaxf(bloy - ly, ly - bhiy), 0.f);
      float ez = fmaxf(fmaxf(bloz - lz, lz - bhiz), 0.f);
      float lb = ex * ex + ey * ey + ez * ez;
      active = !(lb * 0.99999f >= gmax);  // skip only when provably no change
    }
    unsigned long long mask = __ballot(active);
    // ---- B: up to 4 active groups fully interleaved per trip ----
    while (mask) {
      int jj[4];
#pragma unroll
      for (int u = 0; u < 4; ++u) {
        if (mask) { jj[u] = __ffsll((long long)mask) - 1; mask &= mask - 1; }
        else jj[u] = -1;
      }
      float4 P[4]; float od[4];
#pragma unroll
      for (int u = 0; u < 4; ++u)
        if (jj[u] >= 0) {
          int sl = (w + 16 * jj[u]) * 64 + lane;
          P[u] = pts4[sl];
          od[u] = dist_s[sl];
        }
      float nd[4];
#pragma unroll
      for (int u = 0; u < 4; ++u)
        if (jj[u] >= 0) {
          float dx, dy, dz;
          {
#pragma clang fp contract(off)
            dx = P[u].x - lx; dy = P[u].y - ly; dz = P[u].z - lz;
          }
          float d = dist3_exact(dx, dy, dz);
          nd[u] = fminf(od[u], d);
          dist_s[(w + 16 * jj[u]) * 64 + lane] = nd[u];
        }
      float mv[4];
#pragma unroll
      for (int u = 0; u < 4; ++u) mv[u] = (jj[u] >= 0) ? nd[u] : -1.f;
      // four independent 6-level max chains, pipelined level by level
#pragma unroll
      for (int off = 32; off > 0; off >>= 1) {
#pragma unroll
        for (int u = 0; u < 4; ++u)
          if (jj[u] >= 0) mv[u] = fmaxf(mv[u], __shfl_xor(mv[u], off));
      }
#pragma unroll
      for (int u = 0; u < 4; ++u)
        if (jj[u] >= 0) {
          unsigned long long bm = __ballot(nd[u] == mv[u]);
          int l0 = __ffsll((long long)bm) - 1;
          unsigned i0 = (unsigned)__shfl((int)__float_as_uint(P[u].w), l0);
          float xx = __shfl(P[u].x, l0), yy = __shfl(P[u].y, l0),
                zz = __shfl(P[u].z, l0);
          if (__popcll(bm) > 1) {  // exact min-original-idx tie-break (rare)
            unsigned long long m2 = bm;
            unsigned best = 0xffffffffu; int lb2 = l0;
            while (m2) {
              int l = __ffsll((long long)m2) - 1; m2 &= m2 - 1;
              unsigned ii = (unsigned)__shfl((int)__float_as_uint(P[u].w), l);
              if (ii < best) { best = ii; lb2 = l; }
            }
            i0 = best;
            xx = __shfl(P[u].x, lb2); yy = __shfl(P[u].y, lb2);
            zz = __shfl(P[u].z, lb2);
          }
          if (lane == jj[u]) { gmax = mv[u]; gidx = i0; gx_ = xx; gy_ = yy; gz_ = zz; }
        }
    }
    // ---- C: wave winner (f32 max + cheap tie resolve), LDS handoff ----
    float wm = owner ? gmax : -1.f;
#pragma unroll
    for (int off = 32; off > 0; off >>= 1) wm = fmaxf(wm, __shfl_xor(wm, off));
    unsigned long long bm2 = __ballot(owner && (gmax == wm));
    int lw = __ffsll((long long)bm2) - 1;
    if (__popcll(bm2) > 1) {  // two groups tied: min original idx (rare)
      unsigned long long m2 = bm2;
      unsigned best = 0xffffffffu; int lbest = lw;
      while (m2) {
        int l = __ffsll((long long)m2) - 1; m2 &= m2 - 1;
        unsigned ii = (unsigned)__shfl((int)gidx, l);
        if (ii < best) { best = ii; lbest = l; }
      }
      lw = lbest;
    }
    if (lane == lw) {
      wkey_s[par][w] = ((unsigned long long)__float_as_uint(wm) << 32) |
                       (unsigned long long)(~gidx);
      float4 v; v.x = gx_; v.y = gy_; v.z = gz_; v.w = 0.f;
      wxyz_s[par][w] = v;
    }
    __syncthreads();  // the ONLY barrier per iteration
    unsigned long long best = wkey_s[par][0];
    int wi = 0;
#pragma unroll
    for (int i = 1; i < 16; ++i) {
      unsigned long long v = wkey_s[par][i];
      if (v > best) { best = v; wi = i; }
    }
    float4 cc = wxyz_s[par][wi];  // winner coords from LDS (bitwise xyz copy)
    lx = cc.x; ly = cc.y; lz = cc.z;
  }
}

// ---------------- KNN: one wave per center ----------------
#define KNN_TILE 2048

__device__ __forceinline__ float knn_dist_exact(float sn, float cx, float cy,
                                                float cz, float x, float y,
                                                float z) {
#pragma clang fp contract(off)
  float sx = (x * x + y * y) + z * z;
  float dot = (cx * x + cy * y) + cz * z;
  return (sn - 2.0f * dot) + sx;
}

__global__ __launch_bounds__(256) void knn_kernel(
    const float* __restrict__ xyz, const float* __restrict__ nxyz,
    int* __restrict__ knn_out) {
  __shared__ float txyz[KNN_TILE * 3];
  const int lane = threadIdx.x & 63;
  const int wv = threadIdx.x >> 6;
  const int m = blockIdx.x * 4 + wv;
  const bool active = (m < M_SAMPLES);

  float cx = 0.f, cy = 0.f, cz = 0.f;
  if (active) {
    cx = nxyz[3 * m + 0]; cy = nxyz[3 * m + 1]; cz = nxyz[3 * m + 2];
  }
  float sn;
  {
#pragma clang fp contract(off)
    sn = (cx * cx + cy * cy) + cz * cz;
  }

  float hd[K_NN];
  int hi[K_NN];
#pragma unroll
  for (int i = 0; i < K_NN; ++i) { hd[i] = 3.4e38f; hi[i] = 0x7fffffff; }

  for (int base = 0; base < N_PTS; base += KNN_TILE) {
    const int cnt = min(KNN_TILE, N_PTS - base);
    __syncthreads();
    {
      const float4* src4 = (const float4*)(xyz + (size_t)base * 3);
      float4* dst4 = (float4*)txyz;
      const int n4 = (cnt * 3) >> 2;
      for (int i = threadIdx.x; i < n4; i += 256) dst4[i] = src4[i];
    }
    __syncthreads();
    for (int p = lane; p < cnt; p += 64) {
      float x = txyz[3 * p + 0], y = txyz[3 * p + 1], z = txyz[3 * p + 2];
      float d = knn_dist_exact(sn, cx, cy, cz, x, y, z);
      int gi = base + p;
      if (d < hd[K_NN - 1] || (d == hd[K_NN - 1] && gi < hi[K_NN - 1])) {
        hd[K_NN - 1] = d;
        hi[K_NN - 1] = gi;
#pragma unroll
        for (int i = K_NN - 1; i > 0; --i) {
          bool sw = (hd[i] < hd[i - 1]) ||
                    (hd[i] == hd[i - 1] && hi[i] < hi[i - 1]);
          if (sw) {
            float td = hd[i]; hd[i] = hd[i - 1]; hd[i - 1] = td;
            int ti = hi[i]; hi[i] = hi[i - 1]; hi[i - 1] = ti;
          }
        }
      }
    }
  }

  int keep = 0;
#pragma unroll 1
  for (int r = 0; r < K_NN; ++r) {
    float d0 = hd[0];
    int i0 = hi[0];
    int l0 = lane;
#pragma unroll
    for (int off = 32; off > 0; off >>= 1) {
      float od = __shfl_xor(d0, off);
      int oi = __shfl_xor(i0, off);
      int ol = __shfl_xor(l0, off);
      if (od < d0 || (od == d0 && oi < i0)) { d0 = od; i0 = oi; l0 = ol; }
    }
    if (lane == r) keep = i0;
    if (lane == l0) {
#pragma unroll
      for (int i = 0; i < K_NN - 1; ++i) { hd[i] = hd[i + 1]; hi[i] = hi[i + 1]; }
      hd[K_NN - 1] = 3.4e38f;
      hi[K_NN - 1] = 0x7fffffff;
    }
  }
  if (active && lane < K_NN) knn_out[m * K_NN + lane] = keep;
}

// -------- gather + LayerNorm + Linear + maxpool: one block per center --------
__global__ __launch_bounds__(128) void head_kernel(
    const float* __restrict__ feats, const int* __restrict__ knn,
    const float* __restrict__ lnw, const float* __restrict__ lnb,
    const float* __restrict__ W, float* __restrict__ out,
    float* __restrict__ noff) {
  const int m = blockIdx.x;
  const int t = threadIdx.x;
  __shared__ float g[K_NN][68];
  __shared__ float mu_s[K_NN], rs_s[K_NN];

  for (int q = t; q < 256; q += 128) {
    int k = q >> 4, c4 = q & 15;
    int src = knn[m * K_NN + k];
    float4 v = ((const float4*)(feats + (size_t)src * C_IN))[c4];
    g[k][c4 * 4 + 0] = v.x;
    g[k][c4 * 4 + 1] = v.y;
    g[k][c4 * 4 + 2] = v.z;
    g[k][c4 * 4 + 3] = v.w;
  }
  __syncthreads();
  if (t < K_NN) {
    float s = 0.f;
    for (int c = 0; c < C_IN; ++c) s += g[t][c];
    float mu = s * (1.0f / 64.0f);
    float v = 0.f;
    for (int c = 0; c < C_IN; ++c) {
      float d = g[t][c] - mu;
      v += d * d;
    }
    v *= (1.0f / 64.0f);
    mu_s[t] = mu;
    rs_s[t] = rsqrtf(v + 1e-5f);
  }
  __syncthreads();
  for (int q = t; q < K_NN * C_IN; q += 128) {
    int k = q >> 6, c = q & 63;
    g[k][c] = (g[k][c] - mu_s[k]) * rs_s[k] * lnw[c] + lnb[c];
  }
  __syncthreads();
  float acc[K_NN];
#pragma unroll
  for (int k = 0; k < K_NN; ++k) acc[k] = 0.f;
  for (int c = 0; c < C_IN; ++c) {
    float wv = W[c * C_OUT + t];
#pragma unroll
    for (int k = 0; k < K_NN; ++k) acc[k] = fmaf(g[k][c], wv, acc[k]);
  }
  float mx = acc[0];
#pragma unroll
  for (int k = 1; k < K_NN; ++k) mx = fmaxf(mx, acc[k]);
  out[(size_t)m * C_OUT + t] = mx;

  if (m == 0 && t == 0) noff[0] = (float)M_SAMPLES;
}

extern "C" void kernel_launch(void* const* d_in, const int* in_sizes, int n_in,
                              void* d_out, int out_size, void* d_ws,
                              size_t ws_size, hipStream_t stream) {
  const float* feats = (const float*)d_in[0];
  const float* xyz = (const float*)d_in[1];
  const float* lnw = (const float*)d_in[3];
  const float* lnb = (const float*)d_in[4];
  const float* W = (const float*)d_in[5];

  float* out = (float*)d_out;
  float* nxyz = out + (size_t)M_SAMPLES * C_OUT;
  float* noff = nxyz + (size_t)M_SAMPLES * 3;

  char* ws = (char*)d_ws;
  int* hist = (int*)(ws + 0);                 // 512 ints
  int* cursor = (int*)(ws + 2048);            // 512 ints
  float4* pts4 = (float4*)(ws + 4096);        // 40000 float4 = 640000 B
  float* bboxg = (float*)(ws + 644096);       // 625*8 f = 20000 B
  int* knn = (int*)(ws + 664096);             // 10001*16 ints

  hipMemsetAsync(hist, 0, 512 * sizeof(int), stream);
  hist_kernel<<<(N_PTS + 255) / 256, 256, 0, stream>>>(xyz, hist);
  scan_kernel<<<1, 512, 0, stream>>>(hist, cursor);
  scatter_kernel<<<(N_PTS + 255) / 256, 256, 0, stream>>>(xyz, cursor, pts4);
  bbox_kernel<<<NGROUPS, 64, 0, stream>>>(pts4, bboxg);
  fps_kernel<<<1, 1024, 0, stream>>>(xyz, pts4, bboxg, nxyz);
  knn_kernel<<<(M_SAMPLES + 3) / 4, 256, 0, stream>>>(xyz, nxyz, knn);
  head_kernel<<<M_SAMPLES, 128, 0, stream>>>(feats, knn, lnw, lnb, W, out, noff);
}